// Round 1
// baseline (292.951 us; speedup 1.0000x reference)
//
#include <hip/hip_runtime.h>

#define NN   16
#define CC   3
#define FOUT 64
#define HH   256
#define WW   256
#define KK   3
#define HO   254
#define WO   254

__global__ __launch_bounds__(256) void conv2dcq_kernel(
    const float* __restrict__ x,       // (N, C, H, W)
    const float* __restrict__ weight,  // (F, C, K, K)
    const float* __restrict__ bias,    // (F,)
    float* __restrict__ out)           // (N, F, HO, WO)
{
    __shared__ float w_lds[FOUT][9];
    __shared__ float b_lds[FOUT];

    const int tid = threadIdx.x;

    // Stage the used weight slice (channel C-1) + bias into LDS once per block.
    for (int idx = tid; idx < FOUT * 9; idx += 256) {
        const int f = idx / 9, k = idx - f * 9;
        w_lds[f][k] = weight[f * (CC * KK * KK) + (CC - 1) * (KK * KK) + k];
    }
    if (tid < FOUT) b_lds[tid] = bias[tid];
    __syncthreads();

    const int lane  = tid & 63;
    const int wave  = tid >> 6;
    const int gwave = blockIdx.x * 4 + wave;   // 0 .. 16*254-1, one wave per output row
    const int n  = gwave / HO;
    const int i  = gwave - n * HO;             // output row
    const int j0 = lane * 4;                   // output col start (lane 63 -> 252, 2 valid cols)

    // Load input patch: channel 0, rows i..i+2, cols j0..j0+5 (registers).
    const float* xp = x + (size_t)n * (CC * HH * WW) + (size_t)i * WW + j0;
    float in[3][6];
    const bool tail = (j0 + 4 >= WW);          // lane 63 only
    #pragma unroll
    for (int r = 0; r < 3; ++r) {
        const float4 v4 = *(const float4*)(xp + r * WW);   // 16B aligned: j0 % 4 == 0
        in[r][0] = v4.x; in[r][1] = v4.y; in[r][2] = v4.z; in[r][3] = v4.w;
        if (!tail) {
            const float2 v2 = *(const float2*)(xp + r * WW + 4);
            in[r][4] = v2.x; in[r][5] = v2.y;
        } else {
            in[r][4] = 0.f;  in[r][5] = 0.f;   // unused (outputs masked off)
        }
    }

    float* op = out + (size_t)n * FOUT * (HO * WO) + (size_t)i * WO + j0;
    const bool store_hi = (j0 + 3 < WO);       // lane 63 skips cols 254,255

    for (int f = 0; f < FOUT; ++f) {
        float w[9];
        #pragma unroll
        for (int k = 0; k < 9; ++k) w[k] = w_lds[f][k];   // uniform addr -> LDS broadcast
        const float b = b_lds[f];

        float a0 = b, a1 = b, a2 = b, a3 = b;
        #pragma unroll
        for (int a = 0; a < 3; ++a) {
            #pragma unroll
            for (int q = 0; q < 3; ++q) {
                const float wv = w[a * 3 + q];
                a0 = fmaf(wv, in[a][q + 0], a0);
                a1 = fmaf(wv, in[a][q + 1], a1);
                a2 = fmaf(wv, in[a][q + 2], a2);
                a3 = fmaf(wv, in[a][q + 3], a3);
            }
        }

        // Row stride = 254 floats = 1016 B (mod 8 == 0): float2 always aligned.
        *(float2*)(op)     = make_float2(a0, a1);
        if (store_hi)
            *(float2*)(op + 2) = make_float2(a2, a3);
        op += HO * WO;
    }
}

extern "C" void kernel_launch(void* const* d_in, const int* in_sizes, int n_in,
                              void* d_out, int out_size, void* d_ws, size_t ws_size,
                              hipStream_t stream) {
    const float* x      = (const float*)d_in[0];
    const float* weight = (const float*)d_in[1];
    const float* bias   = (const float*)d_in[2];
    float* out          = (float*)d_out;

    const int total_waves = NN * HO;           // 4064 rows, one wave each
    const int blocks = total_waves / 4;        // 4 waves per block = 1016 blocks
    conv2dcq_kernel<<<blocks, 256, 0, stream>>>(x, weight, bias, out);
}

// Round 2
// 290.300 us; speedup vs baseline: 1.0091x; 1.0091x over previous
//
#include <hip/hip_runtime.h>

#define NN   16
#define CC   3
#define FOUT 64
#define HH   256
#define WW   256
#define KK   3
#define HO   254
#define WO   254

__global__ __launch_bounds__(256) void conv2dcq_kernel(
    const float* __restrict__ x,       // (N, C, H, W)
    const float* __restrict__ weight,  // (F, C, K, K)
    const float* __restrict__ bias,    // (F,)
    float* __restrict__ out)           // (N, F, HO, WO)
{
    __shared__ float w_lds[FOUT][9];
    __shared__ float b_lds[FOUT];

    const int tid = threadIdx.x;

    // Stage the used weight slice (channel C-1) + bias into LDS once per block.
    for (int idx = tid; idx < FOUT * 9; idx += 256) {
        const int f = idx / 9, k = idx - f * 9;
        w_lds[f][k] = weight[f * (CC * KK * KK) + (CC - 1) * (KK * KK) + k];
    }
    if (tid < FOUT) b_lds[tid] = bias[tid];
    __syncthreads();

    const int lane  = tid & 63;
    const int wave  = tid >> 6;
    const int gwave = blockIdx.x * 4 + wave;   // 0 .. 16*254-1, one wave per output row
    const int n  = gwave / HO;
    const int i  = gwave - n * HO;             // output row

    // Lane l owns output cols {2l, 2l+1} (region A) and {128+2l, 128+2l+1} (region B).
    // Each float2 store is then CONTIGUOUS across the wave (512B dense burst).
    const int jA = 2 * lane;                   // 0..126, always valid (jA+1 <= 127 < 254)
    const int jB = 128 + 2 * lane;             // 128..254; lane 63 invalid (254 >= WO)
    const bool validB = (jB + 1 < WO);         // lanes 0..62

    // Input patches: channel 0, rows i..i+2, cols jA..jA+3 and jB..jB+3.
    // (jA, jB even -> 8B-aligned float2 loads.)
    const float* xp = x + (size_t)n * (CC * HH * WW) + (size_t)i * WW;
    float inA[3][4], inB[3][4];
    #pragma unroll
    for (int r = 0; r < 3; ++r) {
        const float2 a0 = *(const float2*)(xp + r * WW + jA);
        const float2 a1 = *(const float2*)(xp + r * WW + jA + 2);
        inA[r][0] = a0.x; inA[r][1] = a0.y; inA[r][2] = a1.x; inA[r][3] = a1.y;
        const float2 b0 = *(const float2*)(xp + r * WW + jB);
        const float2 b1 = *(const float2*)(xp + r * WW + jB + 2);
        inB[r][0] = b0.x; inB[r][1] = b0.y; inB[r][2] = b1.x; inB[r][3] = b1.y;
    }

    float* opA = out + (size_t)n * FOUT * (HO * WO) + (size_t)i * WO + jA;
    float* opB = out + (size_t)n * FOUT * (HO * WO) + (size_t)i * WO + jB;

    for (int f = 0; f < FOUT; ++f) {
        float w[9];
        #pragma unroll
        for (int k = 0; k < 9; ++k) w[k] = w_lds[f][k];   // uniform addr -> LDS broadcast
        const float b = b_lds[f];

        float a0 = b, a1 = b, b0 = b, b1 = b;
        #pragma unroll
        for (int a = 0; a < 3; ++a) {
            #pragma unroll
            for (int q = 0; q < 3; ++q) {
                const float wv = w[a * 3 + q];
                a0 = fmaf(wv, inA[a][q + 0], a0);
                a1 = fmaf(wv, inA[a][q + 1], a1);
                b0 = fmaf(wv, inB[a][q + 0], b0);
                b1 = fmaf(wv, inB[a][q + 1], b1);
            }
        }

        *(float2*)(opA) = make_float2(a0, a1);   // wave-contiguous 512B burst
        if (validB)
            *(float2*)(opB) = make_float2(b0, b1); // wave-contiguous 504B burst
        opA += HO * WO;
        opB += HO * WO;
    }
}

extern "C" void kernel_launch(void* const* d_in, const int* in_sizes, int n_in,
                              void* d_out, int out_size, void* d_ws, size_t ws_size,
                              hipStream_t stream) {
    const float* x      = (const float*)d_in[0];
    const float* weight = (const float*)d_in[1];
    const float* bias   = (const float*)d_in[2];
    float* out          = (float*)d_out;

    const int total_waves = NN * HO;           // 4064 rows, one wave each
    const int blocks = total_waves / 4;        // 4 waves per block = 1016 blocks
    conv2dcq_kernel<<<blocks, 256, 0, stream>>>(x, weight, bias, out);
}